// Round 15
// baseline (151.435 us; speedup 1.0000x reference)
//
#include <hip/hip_runtime.h>
#include <hip/hip_fp16.h>

#define NN 50000
#define NE 800000
#define HID 128
#define NSL 128                      // edge slices
#define EPS (NE / NSL)               // 6250 edges per slice
#define NRG 4                        // node ranges of 16384
#define HB  (NRG * NSL)              // 512 histogram blocks
#define PLW 4096                     // packed words (ints) per (slice,range) plane
#define GEMMB ((NN + 63) / 64)       // 782 gemm blocks
#define FILLB ((NE + 255) / 256)     // 3125 per-edge fill blocks
#define SCB ((NN + 1023) / 1024)     // 49 scan blocks

typedef _Float16 f16x8 __attribute__((ext_vector_type(8)));
typedef float f32x4 __attribute__((ext_vector_type(4)));

static __device__ __forceinline__ float lrelu(float x) { return x > 0.f ? x : 0.01f * x; }

// ---------------- MFMA GEMM compute (Wt already staged+swizzled in LDS; caller syncs) ----------------
template <bool AF16, bool SCALE>
static __device__ __forceinline__ void gemm_compute(const void* __restrict__ A,
                                                    const float* __restrict__ nout,
                                                    _Float16* __restrict__ Y, int r0, int n,
                                                    const _Float16* Wt) {
    int t = threadIdx.x;
    int wid = t >> 6, lane = t & 63;
    int kgrp = lane >> 4, l15 = lane & 15;

    int r = r0 + wid * 16 + l15;
    f16x8 a[4];
    #pragma unroll
    for (int ks = 0; ks < 4; ks++)
        #pragma unroll
        for (int j = 0; j < 8; j++) a[ks][j] = (_Float16)0.f;
    if (r < n) {
        if (AF16) {
            const _Float16* Ah = (const _Float16*)A + (size_t)r * HID + kgrp * 8;
            #pragma unroll
            for (int ks = 0; ks < 4; ks++) a[ks] = *(const f16x8*)(Ah + ks * 32);
        } else {
            const float* Af = (const float*)A + (size_t)r * HID + kgrp * 8;
            #pragma unroll
            for (int ks = 0; ks < 4; ks++) {
                float4 lo = *(const float4*)(Af + ks * 32);
                float4 hi = *(const float4*)(Af + ks * 32 + 4);
                a[ks][0] = (_Float16)lo.x; a[ks][1] = (_Float16)lo.y;
                a[ks][2] = (_Float16)lo.z; a[ks][3] = (_Float16)lo.w;
                a[ks][4] = (_Float16)hi.x; a[ks][5] = (_Float16)hi.y;
                a[ks][6] = (_Float16)hi.z; a[ks][7] = (_Float16)hi.w;
            }
        }
    }
    __syncthreads();

    f32x4 acc[8];
    #pragma unroll
    for (int td = 0; td < 8; td++)
        #pragma unroll
        for (int j = 0; j < 4; j++) acc[td][j] = 0.f;

    const char* base = (const char*)Wt;
    #pragma unroll
    for (int ks = 0; ks < 4; ks++) {
        #pragma unroll
        for (int td = 0; td < 8; td++) {
            int c = td * 16 + l15;
            int addr = ((c << 8) + 64 * ks + 16 * kgrp) ^ ((c & 7) << 4);
            f16x8 bfr = *(const f16x8*)(base + addr);
            acc[td] = __builtin_amdgcn_mfma_f32_16x16x32_f16(a[ks], bfr, acc[td], 0, 0, 0);
        }
    }

    int ro = r0 + wid * 16 + kgrp * 4;   // C/D: col = lane&15, row = (lane>>4)*4 + reg
    float no[4] = {1.f, 1.f, 1.f, 1.f};
    if (SCALE) {
        #pragma unroll
        for (int reg = 0; reg < 4; reg++) {
            int orow = ro + reg;
            if (orow < n) no[reg] = nout[orow];
        }
    }
    #pragma unroll
    for (int td = 0; td < 8; td++) {
        #pragma unroll
        for (int reg = 0; reg < 4; reg++) {
            int orow = ro + reg;
            if (orow < n) Y[(size_t)orow * HID + td * 16 + l15] = (_Float16)(acc[td][reg] * no[reg]);
        }
    }
}

// ------- phase1: hist (512) || W2 convert (64, also zeroes done) || GEMM-1 self-converting -------
__global__ __launch_bounds__(256) void phase1(const int* __restrict__ src, const int* __restrict__ dst,
                                              unsigned char* __restrict__ rank_local,
                                              int* __restrict__ H_in, int* __restrict__ H_out,
                                              const float* __restrict__ W1, const float* __restrict__ W2,
                                              _Float16* __restrict__ W2o, int* __restrict__ done,
                                              const float* __restrict__ feat, _Float16* __restrict__ Yh,
                                              int n) {
    __shared__ __align__(16) int lds[2 * PLW];       // 32 KB slab
    int b = blockIdx.x, t = threadIdx.x;
    if (b < HB) {
        int r = b & 3, s = b >> 2;
        #pragma unroll
        for (int i = t; i < (2 * PLW) / 4; i += 256) ((int4*)lds)[i] = make_int4(0, 0, 0, 0);
        __syncthreads();
        int* hin  = lds;
        int* hout = lds + PLW;
        int e0 = s * EPS;
        for (int i = t; i < EPS; i += 256) {
            int e = e0 + i;
            int sd = src[e];
            int dd = dst[e];
            if ((sd >> 14) == r) atomicAdd(&hout[(sd & 16383) >> 2], 1 << ((sd & 3) << 3));
            if ((dd >> 14) == r) {
                int old = atomicAdd(&hin[(dd & 16383) >> 2], 1 << ((dd & 3) << 3));
                rank_local[e] = (unsigned char)((old >> ((dd & 3) << 3)) & 0xff);
            }
        }
        __syncthreads();
        int4* gi = (int4*)(H_in  + (size_t)(s * NRG + r) * PLW);
        int4* go = (int4*)(H_out + (size_t)(s * NRG + r) * PLW);
        #pragma unroll
        for (int i = t; i < PLW / 4; i += 256) {
            gi[i] = ((int4*)hin)[i];
            go[i] = ((int4*)hout)[i];
        }
        return;
    }
    if (b < HB + 64) {
        if (b == HB && t == 0) *done = 0;            // reset ticket for scan1k (replay-safe)
        int j = (b - HB) * 256 + t;                  // 0..16383: W2 -> transposed pre-swizzled fp16
        int p = j * 2;
        int q = p ^ (((p >> 8) & 7) << 4);
        int c = q >> 8;
        int k = (q & 255) >> 1;
        W2o[j] = (_Float16)W2[k * 128 + c];
        return;
    }
    // ---- GEMM-1 with in-block W1 conversion ----
    _Float16* Wt = (_Float16*)lds;
    #pragma unroll
    for (int i = 0; i < 64; i++) {
        int m = t + i * 256;
        int k = m >> 7, c = m & 127;
        int q = (c << 8) | (k << 1);
        int p = q ^ (((q >> 8) & 7) << 4);
        Wt[p >> 1] = (_Float16)W1[m];
    }
    gemm_compute<false, false>(feat, nullptr, Yh, (b - HB - 64) * 64, n, Wt);
}

// ---------------- GEMM layer 2 (fp16 A, out scaled by norm_out row) ----------------
__global__ __launch_bounds__(256) void gemm2(const _Float16* __restrict__ Xh,
                                             const _Float16* __restrict__ W2sw,
                                             const float* __restrict__ nout,
                                             _Float16* __restrict__ Yh, int n) {
    __shared__ __align__(16) _Float16 Wt[16384];
    int t = threadIdx.x;
    #pragma unroll
    for (int i = 0; i < 8; i++) {
        int idx = t + i * 256;
        *(((float4*)Wt) + idx) = ((const float4*)W2sw)[idx];
    }
    gemm_compute<true, true>(Xh, nout, Yh, blockIdx.x * 64, n, Wt);
}

// ---- prefix_k: packed-byte exclusive prefix over slices (in-place -> P) + degrees + norms ----
__global__ void prefix_k(int* __restrict__ H_in, const int* __restrict__ H_out,
                         int* __restrict__ deg_in,
                         float* __restrict__ norm_in, float* __restrict__ norm_out) {
    int tid = blockIdx.x * 256 + threadIdx.x;   // 0..16383
    int r = tid >> 12, w = tid & 4095;
    int runIn = 0, runOut = 0;
    for (int s = 0; s < NSL; s++) {
        size_t idx = ((size_t)(s * NRG + r) << 12) + w;
        int hv = H_in[idx];
        H_in[idx] = runIn;
        runIn += hv;
        runOut += H_out[idx];
    }
    #pragma unroll
    for (int k = 0; k < 4; k++) {
        int n = (r << 14) | (w << 2) | k;
        if (n < NN) {
            int di = (runIn >> (k * 8)) & 0xff;
            int dd = (runOut >> (k * 8)) & 0xff;
            deg_in[n] = di;
            norm_in[n]  = rsqrtf((float)max(di, 1));
            norm_out[n] = rsqrtf((float)max(dd, 1));
        }
    }
}

// ---- scan1k: block scans + last-done block performs the 49-value top-level scan inline ----
__global__ __launch_bounds__(1024) void scan1k(const int* __restrict__ deg_in,
                                               int* __restrict__ off_p, int* __restrict__ bsums,
                                               int* __restrict__ boff, int* __restrict__ done, int n) {
    __shared__ int ws[16];
    __shared__ int lastFlag;
    int t = threadIdx.x;
    int i = blockIdx.x * 1024 + t;
    int v = (i < n) ? deg_in[i] : 0;
    int x = v;
    #pragma unroll
    for (int o = 1; o < 64; o <<= 1) {
        int y = __shfl_up(x, o, 64);
        if ((t & 63) >= o) x += y;
    }
    if ((t & 63) == 63) ws[t >> 6] = x;
    __syncthreads();
    if (t < 16) {
        int s = ws[t];
        #pragma unroll
        for (int o = 1; o < 16; o <<= 1) {
            int y = __shfl_up(s, o, 16);
            if (t >= o) s += y;
        }
        ws[t] = s;
    }
    __syncthreads();
    int wid = t >> 6;
    int pre = wid ? ws[wid - 1] : 0;
    if (i < n) off_p[i] = pre + x - v;
    if (t == 1023) {
        bsums[blockIdx.x] = ws[15];
        __threadfence();                                   // release bsums
        lastFlag = (atomicAdd(done, 1) == (int)gridDim.x - 1);
    }
    __syncthreads();
    if (lastFlag) {
        __threadfence();                                   // acquire other blocks' bsums
        if (t < 64) {
            int nb = gridDim.x;                            // 49 <= 64
            int v2 = (t < nb) ? bsums[t] : 0;
            int x2 = v2;
            #pragma unroll
            for (int o = 1; o < 64; o <<= 1) {
                int y = __shfl_up(x2, o, 64);
                if (t >= o) x2 += y;
            }
            if (t < nb) boff[t] = x2 - v2;
            if (t == 63) off_p[n] = x2;                    // absolute total
        }
    }
}

// ---- fill2: per-edge scatter (off_p+boff inline) || 49 blocks emit final off for agg ----
__global__ void fill2(const int* __restrict__ src, const int* __restrict__ dst,
                      const int* __restrict__ off_p, const int* __restrict__ boff,
                      const unsigned char* __restrict__ rank_local,
                      const int* __restrict__ P, int* __restrict__ eidx,
                      int* __restrict__ off_final, int E) {
    int b = blockIdx.x;
    if (b >= FILLB) {
        int blk = b - FILLB;                               // 0..SCB-1
        for (int k = threadIdx.x; k < 1024; k += 256) {
            int idx = blk * 1024 + k;
            if (idx < NN) off_final[idx] = off_p[idx] + boff[blk];
            else if (idx == NN) off_final[NN] = off_p[NN];
        }
        return;
    }
    int e = b * 256 + threadIdx.x;
    if (e < E) {
        int dd = dst[e];
        int s = e / EPS;
        size_t idx = ((size_t)(s * NRG + (dd >> 14)) << 12) + ((dd & 16383) >> 2);
        int pv = (P[idx] >> ((dd & 3) << 3)) & 0xff;
        eidx[off_p[dd] + boff[dd >> 10] + (int)rank_local[e] + pv] = src[e];
    }
}

// ---- fused aggregate (depth-4 fp16 gather) + nin + bias + LN + LeakyReLU ----
template <bool PROJ, bool NOUTG>
__global__ __launch_bounds__(256) void agg_post(const __half* __restrict__ Yh, const int* __restrict__ off,
                                                const int* __restrict__ eidx, const float* __restrict__ nout,
                                                const float* __restrict__ nin,
                                                const float* __restrict__ bias, const float* __restrict__ gam,
                                                const float* __restrict__ bet, __half* __restrict__ Xo,
                                                const float* __restrict__ W3, float* __restrict__ Z, int n) {
    int w = threadIdx.x >> 6, lane = threadIdx.x & 63;
    int r = blockIdx.x * 4 + w;
    if (r >= n) return;
    int grp = lane >> 4;
    int f0 = (lane & 15) * 8;
    int s = off[r], e = off[r + 1];

    float af[8];
    #pragma unroll
    for (int i = 0; i < 8; i++) af[i] = 0.f;

    union U { float4 f; __half2 h[4]; };
    for (int j = s; j < e; j += 16) {
        int i0 = j + grp, i1 = i0 + 4, i2 = i0 + 8, i3 = i0 + 12;
        int s0 = (i0 < e) ? eidx[i0] : -1;
        int s1 = (i1 < e) ? eidx[i1] : -1;
        int s2 = (i2 < e) ? eidx[i2] : -1;
        int s3 = (i3 < e) ? eidx[i3] : -1;
        U u0, u1, u2, u3;
        float n0 = 1.f, n1 = 1.f, n2 = 1.f, n3 = 1.f;
        if (s0 >= 0) u0.f = *(const float4*)&Yh[(size_t)s0 * HID + f0];
        if (s1 >= 0) u1.f = *(const float4*)&Yh[(size_t)s1 * HID + f0];
        if (s2 >= 0) u2.f = *(const float4*)&Yh[(size_t)s2 * HID + f0];
        if (s3 >= 0) u3.f = *(const float4*)&Yh[(size_t)s3 * HID + f0];
        if (NOUTG) {
            if (s0 >= 0) n0 = nout[s0];
            if (s1 >= 0) n1 = nout[s1];
            if (s2 >= 0) n2 = nout[s2];
            if (s3 >= 0) n3 = nout[s3];
        }
        #define ACCUM(S_, U_, N_)                                           \
        if (S_ >= 0) {                                                      \
            _Pragma("unroll")                                               \
            for (int k = 0; k < 4; k++) {                                   \
                float2 f = __half22float2(U_.h[k]);                         \
                if (NOUTG) {                                                \
                    af[2 * k]     = fmaf(N_, f.x, af[2 * k]);               \
                    af[2 * k + 1] = fmaf(N_, f.y, af[2 * k + 1]);           \
                } else {                                                    \
                    af[2 * k] += f.x; af[2 * k + 1] += f.y;                 \
                }                                                           \
            }                                                               \
        }
        ACCUM(s0, u0, n0) ACCUM(s1, u1, n1) ACCUM(s2, u2, n2) ACCUM(s3, u3, n3)
        #undef ACCUM
    }
    #pragma unroll
    for (int i = 0; i < 8; i++) {
        af[i] += __shfl_xor(af[i], 16, 64);
        af[i] += __shfl_xor(af[i], 32, 64);
    }

    float ni = nin[r];
    float4 b0 = *(const float4*)&bias[f0];
    float4 b1 = *(const float4*)&bias[f0 + 4];
    float v[8];
    v[0] = af[0] * ni + b0.x; v[1] = af[1] * ni + b0.y;
    v[2] = af[2] * ni + b0.z; v[3] = af[3] * ni + b0.w;
    v[4] = af[4] * ni + b1.x; v[5] = af[5] * ni + b1.y;
    v[6] = af[6] * ni + b1.z; v[7] = af[7] * ni + b1.w;

    float sum = 0.f;
    #pragma unroll
    for (int i = 0; i < 8; i++) sum += v[i];
    #pragma unroll
    for (int o = 8; o >= 1; o >>= 1) sum += __shfl_xor(sum, o, 64);
    float mu = sum * (1.f / 128.f);

    float d[8], vs = 0.f;
    #pragma unroll
    for (int i = 0; i < 8; i++) { d[i] = v[i] - mu; vs += d[i] * d[i]; }
    #pragma unroll
    for (int o = 8; o >= 1; o >>= 1) vs += __shfl_xor(vs, o, 64);
    float rs = rsqrtf(vs * (1.f / 128.f) + 1e-5f);

    float4 g0 = *(const float4*)&gam[f0];
    float4 g1 = *(const float4*)&gam[f0 + 4];
    float4 e0 = *(const float4*)&bet[f0];
    float4 e1 = *(const float4*)&bet[f0 + 4];
    float x[8];
    x[0] = lrelu(d[0] * rs * g0.x + e0.x);
    x[1] = lrelu(d[1] * rs * g0.y + e0.y);
    x[2] = lrelu(d[2] * rs * g0.z + e0.z);
    x[3] = lrelu(d[3] * rs * g0.w + e0.w);
    x[4] = lrelu(d[4] * rs * g1.x + e1.x);
    x[5] = lrelu(d[5] * rs * g1.y + e1.y);
    x[6] = lrelu(d[6] * rs * g1.z + e1.z);
    x[7] = lrelu(d[7] * rs * g1.w + e1.w);

    if (PROJ) {
        float z0 = 0.f, z1 = 0.f;
        #pragma unroll
        for (int i = 0; i < 8; i++) {
            float2 w3 = *(const float2*)&W3[(f0 + i) * 2];
            z0 = fmaf(x[i], w3.x, z0);
            z1 = fmaf(x[i], w3.y, z1);
        }
        #pragma unroll
        for (int o = 8; o >= 1; o >>= 1) {
            z0 += __shfl_xor(z0, o, 64);
            z1 += __shfl_xor(z1, o, 64);
        }
        if (lane == 0) {
            float no = nout[r];
            *(float2*)&Z[r * 2] = make_float2(z0 * no, z1 * no);
        }
    } else {
        if (grp == 0) {
            union { __half2 h[4]; float4 f; } o;
            o.h[0] = __floats2half2_rn(x[0], x[1]);
            o.h[1] = __floats2half2_rn(x[2], x[3]);
            o.h[2] = __floats2half2_rn(x[4], x[5]);
            o.h[3] = __floats2half2_rn(x[6], x[7]);
            *(float4*)&Xo[(size_t)r * HID + f0] = o.f;
        }
    }
}

// ---------------- final aggregation (2 dims), 4-way unrolled ----------------
__global__ void agg3(const float* __restrict__ Z, const int* __restrict__ off,
                     const int* __restrict__ eidx, const float* __restrict__ nin,
                     const float* __restrict__ b3, float* __restrict__ out, int n) {
    int r = blockIdx.x * blockDim.x + threadIdx.x;
    if (r < n) {
        int s = off[r], e = off[r + 1];
        float p0 = 0.f, p1 = 0.f, q0 = 0.f, q1 = 0.f;
        float u0 = 0.f, u1 = 0.f, w0 = 0.f, w1 = 0.f;
        int j = s;
        for (; j + 3 < e; j += 4) {
            float2 v0 = *(const float2*)&Z[eidx[j] * 2];
            float2 v1 = *(const float2*)&Z[eidx[j + 1] * 2];
            float2 v2 = *(const float2*)&Z[eidx[j + 2] * 2];
            float2 v3 = *(const float2*)&Z[eidx[j + 3] * 2];
            p0 += v0.x; p1 += v0.y;
            q0 += v1.x; q1 += v1.y;
            u0 += v2.x; u1 += v2.y;
            w0 += v3.x; w1 += v3.y;
        }
        for (; j < e; ++j) {
            float2 v = *(const float2*)&Z[eidx[j] * 2];
            p0 += v.x; p1 += v.y;
        }
        float a0 = (p0 + q0) + (u0 + w0);
        float a1 = (p1 + q1) + (u1 + w1);
        float ni = nin[r];
        out[r * 2 + 0] = a0 * ni + b3[0];
        out[r * 2 + 1] = a1 * ni + b3[1];
    }
}

extern "C" void kernel_launch(void* const* d_in, const int* in_sizes, int n_in,
                              void* d_out, int out_size, void* d_ws, size_t ws_size,
                              hipStream_t stream) {
    const float* feat = (const float*)d_in[0];
    const int* src = (const int*)d_in[1];
    const int* dst = (const int*)d_in[2];
    const float* W1 = (const float*)d_in[3];
    const float* b1 = (const float*)d_in[4];
    const float* W2 = (const float*)d_in[5];
    const float* b2 = (const float*)d_in[6];
    const float* W3 = (const float*)d_in[7];
    const float* b3 = (const float*)d_in[8];
    const float* g1 = (const float*)d_in[9];
    const float* be1 = (const float*)d_in[10];
    const float* g2 = (const float*)d_in[11];
    const float* be2 = (const float*)d_in[12];
    float* out = (float*)d_out;

    char* p = (char*)d_ws;
    auto carve = [&](size_t bytes) -> char* {
        char* q = p;
        p += (bytes + 255) & ~(size_t)255;
        return q;
    };
    int* deg_in  = (int*)carve(NN * 4);
    float* norm_out = (float*)carve(NN * 4);
    float* norm_in  = (float*)carve(NN * 4);
    int* off_p   = (int*)carve((NN + 1) * 4);
    int* off_f   = (int*)carve((NN + 1) * 4);
    int* bsums   = (int*)carve(64 * 4);
    int* boff    = (int*)carve(64 * 4);
    int* done    = (int*)carve(256);
    int* eidx    = (int*)carve((size_t)NE * 4);
    unsigned char* rank_local = (unsigned char*)carve((size_t)NE);
    int* H_in  = (int*)carve((size_t)NSL * NRG * PLW * 4);   // 8 MB; becomes P in-place
    int* H_out = (int*)carve((size_t)NSL * NRG * PLW * 4);   // 8 MB
    _Float16* W2sw = (_Float16*)carve(16384 * 2);
    _Float16* Yh = (_Float16*)carve((size_t)NN * HID * 2);
    __half* Xh = (__half*)carve((size_t)NN * HID * 2);
    float* Z = (float*)carve((size_t)NN * 2 * 4);

    // phase1: hist || W2 convert (+done reset) || GEMM-1 self-converting
    phase1<<<HB + 64 + GEMMB, 256, 0, stream>>>(src, dst, rank_local, H_in, H_out,
                                                W1, W2, W2sw, done, feat, Yh, NN);

    // packed-byte exclusive prefix over slices (P in-place) + degrees + norms
    prefix_k<<<64, 256, 0, stream>>>(H_in, H_out, deg_in, norm_in, norm_out);

    // one-launch two-level scan (last-done block does the top-level pass)
    scan1k<<<SCB, 1024, 0, stream>>>(deg_in, off_p, bsums, boff, done, NN);

    // CSR fill (atomic-free) || final off emission
    fill2<<<FILLB + SCB, 256, 0, stream>>>(src, dst, off_p, boff, rank_local, H_in, eidx, off_f, NE);

    // layer 1 aggregation (folds nout[src]) -> fp16 X
    agg_post<false, true><<<(NN + 3) / 4, 256, 0, stream>>>((const __half*)Yh, off_f, eidx, norm_out, norm_in,
                                                            b1, g1, be1, Xh, nullptr, nullptr, NN);
    // layer 2 GEMM (fp16 MFMA, output pre-scaled by norm_out)
    gemm2<<<GEMMB, 256, 0, stream>>>((const _Float16*)Xh, W2sw, norm_out, Yh, NN);
    // layer 2 aggregation (Yh pre-scaled) fused with layer-3 projection -> Z
    agg_post<true, false><<<(NN + 3) / 4, 256, 0, stream>>>((const __half*)Yh, off_f, eidx, norm_out, norm_in,
                                                            b2, g2, be2, nullptr, W3, Z, NN);
    // layer 3 aggregation -> out
    agg3<<<(NN + 255) / 256, 256, 0, stream>>>(Z, off_f, eidx, norm_in, b3, out, NN);
}